// Round 4
// baseline (407.128 us; speedup 1.0000x reference)
//
#include <hip/hip_runtime.h>

#define DEV __device__ __forceinline__

// ---------------------------------------------------------------------------
// R10 = R9 (thin waves: 64 lanes/elem x 4 amps/lane, (256,4) bound, VGPR=56,
// no spill, dispatch 57.4us) with ONE change: each wave processes TWO
// elements sequentially -> 1024 blocks instead of 2048.
//   Why: graded dur_us minus rocprof dispatch time scales with BLOCK COUNT
//   (512->6us, 1024->19us, 2048->~70us overhead), not with kernel properties.
//   This round halves blocks at identical total work to test/exploit that:
//   dispatch should stay ~57-68us; graded should drop to ~80-90us if the
//   per-block-overhead theory is right.
//   #pragma unroll 1 on the element loop keeps the live set (and VGPR) at
//   R9 levels — no cross-element CSE that could re-trigger spills.
//
// Basis: lane6 = q0 q2 q4 q6 q1 q3 (bits 5..0), s2 = q5 q7 (bits 1..0).
// All R5/R6 mask tables kept verbatim; compile-time wrappers transform:
// LM' = (LM<<2)|(SM>>2), SM' = SM&3 (same for parity masks).
// ---------------------------------------------------------------------------

DEV int lpar(int lane, int m) { return __builtin_popcount(lane & m) & 1; }
constexpr int cpar(int v) { return (v ^ (v >> 1) ^ (v >> 2) ^ (v >> 3)) & 1; }

// compile-time basis transform: old (mask-over-L, mask-over-S) -> new
constexpr int TLm(int LM, int SM) { return (LM << 2) | (SM >> 2); }  // lane6 mask
constexpr int TSm(int SM) { return SM & 3; }                         // s2 mask

// ---- real RY, NEW-basis masks (4 amps/lane) -------------------------------
template<int LM, int SM, int LR, int SR>
DEV void ryr(float* p, float gc, float gs, int lane) {
  const float sg0 = lpar(lane, LR) ? gs : -gs;   // sign when cpar(s&SR)==0
  const float sg1 = -sg0;
  if constexpr (LM != 0) {
    float t[4];
    #pragma unroll
    for (int s = 0; s < 4; ++s) t[s] = __shfl_xor(p[s ^ SM], LM);
    #pragma unroll
    for (int s = 0; s < 4; ++s)
      p[s] = gc * p[s] + (cpar(s & SR) ? sg1 : sg0) * t[s];
  } else {
    constexpr int LOW = SM & (-SM);
    #pragma unroll
    for (int s = 0; s < 4; ++s) if (!(s & LOW)) {
      const int s1 = s ^ SM;
      float a = p[s], b = p[s1];
      float sg = cpar(s & SR) ? sg1 : sg0;
      p[s]  = gc * a + sg * b;
      p[s1] = gc * b - sg * a;
    }
  }
}

// ---- complex U3, NEW-basis masks ------------------------------------------
template<int LM, int SM, int LR, int SR>
DEV void u3_g(float* pr, float* pi, const float* u, int lane) {
  const bool hl = lpar(lane, LR);
  const float d0r = hl ? u[6] : u[0], d0i = hl ? u[7] : u[1];
  const float o0r = hl ? u[4] : u[2], o0i = hl ? u[5] : u[3];
  const float d1r = hl ? u[0] : u[6], d1i = hl ? u[1] : u[7];
  const float o1r = hl ? u[2] : u[4], o1i = hl ? u[3] : u[5];
  if constexpr (LM != 0) {
    float tr[4], ti[4];
    #pragma unroll
    for (int s = 0; s < 4; ++s) {
      tr[s] = __shfl_xor(pr[s ^ SM], LM);
      ti[s] = __shfl_xor(pi[s ^ SM], LM);
    }
    #pragma unroll
    for (int s = 0; s < 4; ++s) {
      const bool c1 = cpar(s & SR);
      const float dr = c1 ? d1r : d0r, di = c1 ? d1i : d0i;
      const float orr = c1 ? o1r : o0r, oi = c1 ? o1i : o0i;
      float ar = pr[s], ai = pi[s];
      pr[s] = dr*ar - di*ai + orr*tr[s] - oi*ti[s];
      pi[s] = dr*ai + di*ar + orr*ti[s] + oi*tr[s];
    }
  } else {
    constexpr int LOW = SM & (-SM);
    #pragma unroll
    for (int s = 0; s < 4; ++s) if (!(s & LOW)) {
      const int s1 = s ^ SM;
      const bool c1 = cpar(s & SR);
      const float dAr = c1 ? d1r : d0r, dAi = c1 ? d1i : d0i;
      const float oAr = c1 ? o1r : o0r, oAi = c1 ? o1i : o0i;
      const float dBr = c1 ? d0r : d1r, dBi = c1 ? d0i : d1i;
      const float oBr = c1 ? o0r : o1r, oBi = c1 ? o0i : o1i;
      float ar = pr[s], ai = pi[s], br = pr[s1], bi = pi[s1];
      pr[s]  = dAr*ar - dAi*ai + oAr*br - oAi*bi;
      pi[s]  = dAr*ai + dAi*ar + oAr*bi + oAi*br;
      pr[s1] = dBr*br - dBi*bi + oBr*ar - oBi*ai;
      pi[s1] = dBr*bi + dBi*br + oBr*ai + oBi*ar;
    }
  }
}

// ---- CRX, NEW-basis masks -------------------------------------------------
template<int LMt, int SMt, int LRc, int SRc>
DEV void crx_g(float* pr, float* pi, float c, float s_, int lane) {
  const bool hl = lpar(lane, LRc);
  const float cc0 = hl ? c : 1.0f, ss0 = hl ? s_ : 0.0f;
  const float cc1 = hl ? 1.0f : c, ss1 = hl ? 0.0f : s_;
  if constexpr (LMt != 0) {
    float tr[4], ti[4];
    #pragma unroll
    for (int s = 0; s < 4; ++s) {
      tr[s] = __shfl_xor(pr[s ^ SMt], LMt);
      ti[s] = __shfl_xor(pi[s ^ SMt], LMt);
    }
    #pragma unroll
    for (int s = 0; s < 4; ++s) {
      const bool c1 = cpar(s & SRc);
      const float cc = c1 ? cc1 : cc0, ss = c1 ? ss1 : ss0;
      float ar = pr[s], ai = pi[s];
      pr[s] = cc * ar + ss * ti[s];
      pi[s] = cc * ai - ss * tr[s];
    }
  } else {
    constexpr int LOW = SMt & (-SMt);
    #pragma unroll
    for (int s = 0; s < 4; ++s) if (!(s & LOW)) {
      const int s1 = s ^ SMt;
      const bool c1 = cpar(s & SRc);
      const float cc = c1 ? cc1 : cc0, ss = c1 ? ss1 : ss0;
      float ar = pr[s], ai = pi[s], br = pr[s1], bi = pi[s1];
      pr[s]  = cc * ar + ss * bi;
      pi[s]  = cc * ai - ss * br;
      pr[s1] = cc * br + ss * ai;
      pi[s1] = cc * bi - ss * ar;
    }
  }
}

// ---- U4 (fused entangler), NEW-basis masks --------------------------------
#define U4CLASS(Q)                                                            \
  if constexpr (!(((SRc == 0) && (Q & 2)) || ((SRt == 0) && (Q & 1)))) {      \
    const int r1 = R ^ Q, r2 = r1 ^ 2;                                        \
    const float2 wd = w2[r1 * 4 + r1],       wo = w2[r1 * 4 + (r1 ^ 1)];      \
    const float2 vd = w2[r2 * 4 + r1],       vo = w2[r2 * 4 + (r1 ^ 1)];      \
    _Pragma("unroll")                                                         \
    for (int s = 0; s < 4; ++s)                                               \
      if (((cpar(s & SRc) << 1) | cpar(s & SRt)) == Q) {                      \
        float ar = pr[s], ai = pi[s], br = tr[s], bi = ti[s];                 \
        pr[s] = wd.x*ar - wd.y*ai + wo.x*br - wo.y*bi;                        \
        pi[s] = wd.x*ai + wd.y*ar + wo.x*bi + wo.y*br;                        \
        tr[s] = vd.x*ar - vd.y*ai + vo.x*br - vo.y*bi;                        \
        ti[s] = vd.x*ai + vd.y*ar + vo.x*bi + vo.y*br;                        \
      }                                                                       \
  }

template<int LMc, int SMc, int LMt, int SMt, int LRc, int SRc, int LRt, int SRt>
DEV void u4_g(float* pr, float* pi, const float2* w2, int lane) {
  const int R = (lpar(lane, LRc) << 1) | lpar(lane, LRt);
  float tr[4], ti[4];
  #pragma unroll
  for (int s = 0; s < 4; ++s) {
    float vr = pr[s ^ SMt], vi = pi[s ^ SMt];
    if constexpr (LMt != 0) { vr = __shfl_xor(vr, LMt); vi = __shfl_xor(vi, LMt); }
    tr[s] = vr; ti[s] = vi;
  }
  U4CLASS(0) U4CLASS(1) U4CLASS(2) U4CLASS(3)
  #pragma unroll
  for (int s = 0; s < 4; ++s) {
    float br = tr[s ^ SMc], bi = ti[s ^ SMc];
    if constexpr (LMc != 0) { br = __shfl_xor(br, LMc); bi = __shfl_xor(bi, LMc); }
    pr[s] += br; pi[s] += bi;
  }
}

// ---- OLD-basis wrappers: keep the verified R5/R6 mask tables verbatim -----
template<int LMc,int SMc,int LMt,int SMt,int LRc,int SRc,int LRt,int SRt>
DEV void u4o(float* pr, float* pi, const float2* w2, int lane) {
  u4_g<TLm(LMc,SMc),TSm(SMc), TLm(LMt,SMt),TSm(SMt),
       TLm(LRc,SRc),TSm(SRc), TLm(LRt,SRt),TSm(SRt)>(pr, pi, w2, lane);
}
template<int LM,int SM,int LR,int SR>
DEV void u3o(float* pr, float* pi, const float* u, int lane) {
  u3_g<TLm(LM,SM),TSm(SM), TLm(LR,SR),TSm(SR)>(pr, pi, u, lane);
}
template<int LMt,int SMt,int LRc,int SRc>
DEV void crxo(float* pr, float* pi, float c, float s_, int lane) {
  crx_g<TLm(LMt,SMt),TSm(SMt), TLm(LRc,SRc),TSm(SRc)>(pr, pi, c, s_, lane);
}

// ---- U3 coefficient build -------------------------------------------------
DEV void u3_make(float t, float p, float l, float* u) {
  float c = __cosf(0.5f * t), s = __sinf(0.5f * t);
  float cp = __cosf(p), sp = __sinf(p);
  float cl = __cosf(l), sl = __sinf(l);
  float cpl = __cosf(p + l), spl = __sinf(p + l);
  u[0] = c;        u[1] = 0.0f;
  u[2] = -cl * s;  u[3] = -sl * s;
  u[4] = cp * s;   u[5] = sp * s;
  u[6] = cpl * c;  u[7] = spl * c;
}

// ---- <Z3>,<Z7>: old (LR=10,SR=1)/(10,0) -> new lane mask 40, s bit0 -------
DEV void expz_fin(const float* pr, const float* pi, int lane, float& z3, float& z7) {
  float t3 = 0.0f, t7 = 0.0f;
  #pragma unroll
  for (int s = 0; s < 4; ++s) {
    float p = pr[s] * pr[s] + pi[s] * pi[s];
    t7 += p;
    t3 += (s & 1) ? -p : p;
  }
  if (lpar(lane, 40)) { t3 = -t3; t7 = -t7; }
  #pragma unroll
  for (int m = 1; m < 64; m <<= 1) {
    t3 += __shfl_xor(t3, m);
    t7 += __shfl_xor(t7, m);
  }
  z3 = t3; z7 = t7;
}

// ---------------------------------------------------------------------------

__global__ __launch_bounds__(256, 4)
void qcnn_kernel(const float* __restrict__ x,
                 const float* __restrict__ rz_p, const float* __restrict__ ry_p,
                 const float* __restrict__ ry2_p, const float* __restrict__ crx_p,
                 const float* __restrict__ u3_p, const float* __restrict__ u3b_p,
                 const float* __restrict__ W1, const float* __restrict__ b1,
                 const float* __restrict__ W2, const float* __restrict__ b2,
                 float* __restrict__ out, int B) {
  __shared__ __align__(8) float cw[64];       // 2 layers x 16 complex fused-U4

  const int tid  = threadIdx.x;
  const int lane = tid & 63;
  const int wave = tid >> 6;
  const int sub  = lane & 15;
  const int elem0 = blockIdx.x * 8 + wave * 2; // 2 elements per wave, serial

  // ---- fused U4 build (wave 0, lanes 0..31; one complex entry per lane) ---
  if (tid < 32) {
    const int lay = tid >> 4, e = tid & 15, i4 = e >> 2, j4 = e & 3;
    const int base = tid & 48;
    const float c45 = 0.70710678118654752f;
    float rz = rz_p[lay], ry = ry_p[lay], ry2 = ry2_p[lay];
    float mr = (i4 == j4) ? c45 : 0.0f;
    float mi = (i4 == j4) ? ((i4 & 1) ? -c45 : c45) : 0.0f;
    { int t = (i4 & 1) ? (i4 ^ 2) : i4; int src = base | (t << 2) | j4;
      mr = __shfl(mr, src); mi = __shfl(mi, src); }
    { float cz = __cosf(0.5f * rz), sz = __sinf(0.5f * rz);
      float di = (i4 & 2) ? sz : -sz;
      float nr = cz * mr - di * mi, ni = cz * mi + di * mr; mr = nr; mi = ni; }
    { float cy = __cosf(0.5f * ry), sy = __sinf(0.5f * ry);
      int src = base | ((i4 ^ 1) << 2) | j4;
      float orr = __shfl(mr, src), oii = __shfl(mi, src);
      float sg = (i4 & 1) ? sy : -sy;
      mr = cy * mr + sg * orr; mi = cy * mi + sg * oii; }
    { int t = (i4 & 2) ? (i4 ^ 1) : i4; int src = base | (t << 2) | j4;
      mr = __shfl(mr, src); mi = __shfl(mi, src); }
    { float cy = __cosf(0.5f * ry2), sy = __sinf(0.5f * ry2);
      int src = base | ((i4 ^ 1) << 2) | j4;
      float orr = __shfl(mr, src), oii = __shfl(mi, src);
      float sg = (i4 & 1) ? sy : -sy;
      mr = cy * mr + sg * orr; mi = cy * mi + sg * oii; }
    { int t = (i4 & 1) ? (i4 ^ 2) : i4; int src = base | (t << 2) | j4;
      mr = __shfl(mr, src); mi = __shfl(mi, src); }
    { float di = (i4 & 2) ? c45 : -c45;
      float nr = c45 * mr - di * mi, ni = c45 * mi + di * mr; mr = nr; mi = ni; }
    cw[(lay * 16 + e) * 2]     = mr;
    cw[(lay * 16 + e) * 2 + 1] = mi;
  }

  __syncthreads();  // cw ready
  const float2* w0 = (const float2*)cw;
  const float2* w1 = ((const float2*)cw) + 16;

  #pragma unroll 1
  for (int ei = 0; ei < 2; ++ei) {
    const int elem  = elem0 + ei;
    const int elemc = elem < B ? elem : (B - 1);

    // ---- angles: lane sub (= lane&15) holds angles 2*sub, 2*sub+1; the
    // pair is replicated 4x across the wave. Broadcast via __shfl from lane
    // k>>1 (< 16).
    float2 aa = ((const float2*)x)[(size_t)elemc * 16 + sub];
    float ch0 = __cosf(0.5f * aa.x), sh0 = __sinf(0.5f * aa.x);
    float ch1 = __cosf(0.5f * aa.y), sh1 = __sinf(0.5f * aa.y);

    float cq[8], sq[8];
    #pragma unroll
    for (int q = 0; q < 8; ++q) {
      cq[q] = __shfl((q & 1) ? ch1 : ch0, q >> 1);
      sq[q] = __shfl((q & 1) ? sh1 : sh0, q >> 1);
    }

    // ---- product-state init (cycle-1 RYs; state real) ---------------------
    // New lane bits (5..0): q0 q2 q4 q6 q1 q3 ; s bits (1..0): q5 q7
    float p[4];
    {
      float g = ((lane & 32) ? sq[0] : cq[0]) * ((lane & 16) ? sq[2] : cq[2]) *
                ((lane & 8)  ? sq[4] : cq[4]) * ((lane & 4)  ? sq[6] : cq[6]) *
                ((lane & 2)  ? sq[1] : cq[1]) * ((lane & 1)  ? sq[3] : cq[3]);
      p[0] = g * cq[5] * cq[7];
      p[1] = g * cq[5] * sq[7];
      p[2] = g * sq[5] * cq[7];
      p[3] = g * sq[5] * sq[7];
    }

    // ---- encode cycles 2..4 (24 real RYs; OLD masks, transformed) ---------
    #define ENC(k, LM, SM, LR, SR) {                                  \
      float gc = __shfl(((k) & 1) ? ch1 : ch0, (k) >> 1);             \
      float gs = __shfl(((k) & 1) ? sh1 : sh0, (k) >> 1);             \
      ryr<TLm(LM,SM), TSm(SM), TLm(LR,SR), TSm(SR)>(p, gc, gs, lane); }

    ENC(8,  8,8, 7,15)  ENC(9,  4,8, 8,8)   ENC(10, 4,4, 12,8)  ENC(11, 2,4, 12,12)
    ENC(12, 2,2, 14,12) ENC(13, 1,2, 14,14) ENC(14, 1,1, 15,14) ENC(15, 8,9, 15,15)
    ENC(16, 12,0, 8,15) ENC(17, 0,12, 15,7) ENC(18, 6,0, 3,15)  ENC(19, 0,6, 15,3)
    ENC(20, 3,0, 1,15)  ENC(21, 0,3, 15,1)  ENC(22, 9,8, 0,15)  ENC(23, 4,9, 15,0)
    ENC(24, 12,12, 2,10) ENC(25, 6,12, 7,8) ENC(26, 6,6, 4,7)   ENC(27, 3,6, 11,4)
    ENC(28, 3,3, 10,11)  ENC(29, 9,11, 5,10) ENC(30, 13,1, 5,5) ENC(31, 8,5, 10,5)
    #undef ENC

    // ---- park real encode state in 4 registers for psi1 -------------------
    const float e0 = p[0], e1 = p[1], e2_ = p[2], e3 = p[3];

    // ---- psi0: conv layers ------------------------------------------------
    float pi_[4] = {0.0f, 0.0f, 0.0f, 0.0f};

    u4o<10,0,  0,10, 8,10, 5,2 >(p, pi_, w0, lane);   // (0,1)
    u4o<5,0,   0,5,  1,5,  10,1>(p, pi_, w0, lane);   // (2,3)
    u4o<10,8,  4,10, 0,10, 5,0 >(p, pi_, w0, lane);   // (4,5)
    u4o<5,4,   2,5,  0,5,  10,0>(p, pi_, w0, lane);   // (6,7)
    u4o<0,10,  5,0,  5,2,  1,5 >(p, pi_, w0, lane);   // (1,2)
    u4o<0,5,   10,8, 10,1, 0,10>(p, pi_, w0, lane);   // (3,4)
    u4o<4,10,  5,4,  5,0,  0,5 >(p, pi_, w0, lane);   // (5,6)
    {
      float ua[8]; u3_make(u3_p[0], u3_p[1], u3_p[2], ua);
      u3o<0,10, 5,2 >(p, pi_, ua, lane);   // q1
      u3o<0,5,  10,1>(p, pi_, ua, lane);   // q3
      u3o<4,10, 5,0 >(p, pi_, ua, lane);   // q5
      u3o<2,5,  10,0>(p, pi_, ua, lane);   // q7
    }
    u4o<0,10,  0,5,  5,2,  10,1>(p, pi_, w1, lane);   // (1,3)
    u4o<4,10,  2,5,  5,0,  10,0>(p, pi_, w1, lane);   // (5,7)
    u4o<0,5,   4,10, 10,1, 5,0 >(p, pi_, w1, lane);   // (3,5)
    {
      float ua[8]; u3_make(u3_p[3], u3_p[4], u3_p[5], ua);
      u3o<0,5,  10,1>(p, pi_, ua, lane);   // q3
      u3o<2,5,  10,0>(p, pi_, ua, lane);   // q7
    }

    float f0, f1;
    expz_fin(p, pi_, lane, f0, f1);

    // ---- psi1: restore enc from registers, CRX ladders + U3b --------------
    p[0] = e0; p[1] = e1; p[2] = e2_; p[3] = e3;
    pi_[0] = 0.0f; pi_[1] = 0.0f; pi_[2] = 0.0f; pi_[3] = 0.0f;

    {
      float t = crx_p[0];
      float cc = __cosf(0.5f * t), ss = __sinf(0.5f * t);
      crxo<0,10, 8,10>(p, pi_, cc, ss, lane);   // (0,1)
      crxo<0,5,  1,5 >(p, pi_, cc, ss, lane);   // (2,3)
      crxo<4,10, 0,10>(p, pi_, cc, ss, lane);   // (4,5)
      crxo<2,5,  0,5 >(p, pi_, cc, ss, lane);   // (6,7)
      crxo<5,0,  5,2 >(p, pi_, cc, ss, lane);   // (1,2)
      crxo<10,8, 10,1>(p, pi_, cc, ss, lane);   // (3,4)
      crxo<5,4,  5,0 >(p, pi_, cc, ss, lane);   // (5,6)
    }
    {
      float ub[8]; u3_make(u3b_p[0], u3b_p[1], u3b_p[2], ub);
      u3o<0,10, 5,2 >(p, pi_, ub, lane);
      u3o<0,5,  10,1>(p, pi_, ub, lane);
      u3o<4,10, 5,0 >(p, pi_, ub, lane);
      u3o<2,5,  10,0>(p, pi_, ub, lane);
    }
    {
      float t = crx_p[1];
      float cc = __cosf(0.5f * t), ss = __sinf(0.5f * t);
      crxo<0,5,  5,2 >(p, pi_, cc, ss, lane);   // (1,3)
      crxo<2,5,  5,0 >(p, pi_, cc, ss, lane);   // (5,7)
      crxo<4,10, 10,1>(p, pi_, cc, ss, lane);   // (3,5)
    }
    {
      float ub[8]; u3_make(u3b_p[3], u3b_p[4], u3b_p[5], ub);
      u3o<0,5,  10,1>(p, pi_, ub, lane);
      u3o<2,5,  10,0>(p, pi_, ub, lane);
    }

    float f2, f3;
    expz_fin(p, pi_, lane, f2, f3);

    // ---- MLP (whole wave = one element) -----------------------------------
    const int j = (lane < 15) ? lane : 0;
    float acc = W1[j * 4 + 0] * f0 + W1[j * 4 + 1] * f1 +
                W1[j * 4 + 2] * f2 + W1[j * 4 + 3] * f3 + b1[j];
    float e2 = __expf(2.0f * acc);
    float th = (e2 - 1.0f) / (e2 + 1.0f);
    float part = (lane < 15) ? th * W2[j] : 0.0f;
    #pragma unroll
    for (int m = 1; m < 64; m <<= 1) part += __shfl_xor(part, m);

    if (lane == 0 && elem < B) {
      float z = part + b2[0];
      out[elem] = 1.0f / (1.0f + __expf(-z));
    }
  }
}

extern "C" void kernel_launch(void* const* d_in, const int* in_sizes, int n_in,
                              void* d_out, int out_size, void* d_ws, size_t ws_size,
                              hipStream_t stream) {
  (void)n_in; (void)out_size; (void)d_ws; (void)ws_size;
  const float* x     = (const float*)d_in[0];
  const float* rz_p  = (const float*)d_in[1];
  const float* ry_p  = (const float*)d_in[2];
  const float* ry2_p = (const float*)d_in[3];
  const float* crx_p = (const float*)d_in[4];
  const float* u3_p  = (const float*)d_in[5];
  const float* u3b_p = (const float*)d_in[6];
  const float* W1    = (const float*)d_in[7];
  const float* b1    = (const float*)d_in[8];
  const float* W2    = (const float*)d_in[9];
  const float* b2    = (const float*)d_in[10];
  float* out = (float*)d_out;

  const int B = in_sizes[0] / 32;          // 8192
  const int blocks = (B + 7) / 8;          // 2 elems/wave, 4 waves/block
  qcnn_kernel<<<dim3(blocks), dim3(256), 0, stream>>>(
      x, rz_p, ry_p, ry2_p, crx_p, u3_p, u3b_p, W1, b1, W2, b2, out, B);
}

// Round 5
// 125.592 us; speedup vs baseline: 3.2417x; 3.2417x over previous
//
#include <hip/hip_runtime.h>

#define DEV __device__ __forceinline__

// ---------------------------------------------------------------------------
// R11 = R9 body VERBATIM (thin waves: 64 lanes/elem x 4 amps/lane, VGPR=56,
// no spill, dispatch 57.4us) with ONLY the launch geometry changed:
//   256-thread blocks (4 waves)  ->  1024-thread blocks (16 waves)
//   => 512 blocks instead of 2048, same 8192 waves, 1 element/wave.
// Why: R10's attempt to cut block count by looping elements inside the wave
// re-triggered the scratch-spill pathology (VGPR=64, 968 MB/dispatch scratch,
// 340us) — the R9 straight-line body is a verified-good codegen island and
// must not be restructured. Meanwhile the graded-vs-dispatch gap is small
// ONLY in 512-block configs (R6: +6us) and large in 2048-block configs
// (R8/R9: ~+70us). This tests/exploits that with zero risk to codegen.
// Resource check: 2 blocks/CU co-resident (LDS 512B, 2048 thr = CU max)
// -> 8 waves/SIMD possible, same as R9. __launch_bounds__(1024,4) keeps the
// 128-VGPR cap that produced R9's sane allocation.
//
// Basis: lane6 = q0 q2 q4 q6 q1 q3 (bits 5..0), s2 = q5 q7 (bits 1..0).
// All R5/R6 mask tables kept verbatim; compile-time wrappers transform:
// LM' = (LM<<2)|(SM>>2), SM' = SM&3 (same for parity masks).
// ---------------------------------------------------------------------------

DEV int lpar(int lane, int m) { return __builtin_popcount(lane & m) & 1; }
constexpr int cpar(int v) { return (v ^ (v >> 1) ^ (v >> 2) ^ (v >> 3)) & 1; }

// compile-time basis transform: old (mask-over-L, mask-over-S) -> new
constexpr int TLm(int LM, int SM) { return (LM << 2) | (SM >> 2); }  // lane6 mask
constexpr int TSm(int SM) { return SM & 3; }                         // s2 mask

// ---- real RY, NEW-basis masks (4 amps/lane) -------------------------------
template<int LM, int SM, int LR, int SR>
DEV void ryr(float* p, float gc, float gs, int lane) {
  const float sg0 = lpar(lane, LR) ? gs : -gs;   // sign when cpar(s&SR)==0
  const float sg1 = -sg0;
  if constexpr (LM != 0) {
    float t[4];
    #pragma unroll
    for (int s = 0; s < 4; ++s) t[s] = __shfl_xor(p[s ^ SM], LM);
    #pragma unroll
    for (int s = 0; s < 4; ++s)
      p[s] = gc * p[s] + (cpar(s & SR) ? sg1 : sg0) * t[s];
  } else {
    constexpr int LOW = SM & (-SM);
    #pragma unroll
    for (int s = 0; s < 4; ++s) if (!(s & LOW)) {
      const int s1 = s ^ SM;
      float a = p[s], b = p[s1];
      float sg = cpar(s & SR) ? sg1 : sg0;
      p[s]  = gc * a + sg * b;
      p[s1] = gc * b - sg * a;
    }
  }
}

// ---- complex U3, NEW-basis masks ------------------------------------------
template<int LM, int SM, int LR, int SR>
DEV void u3_g(float* pr, float* pi, const float* u, int lane) {
  const bool hl = lpar(lane, LR);
  const float d0r = hl ? u[6] : u[0], d0i = hl ? u[7] : u[1];
  const float o0r = hl ? u[4] : u[2], o0i = hl ? u[5] : u[3];
  const float d1r = hl ? u[0] : u[6], d1i = hl ? u[1] : u[7];
  const float o1r = hl ? u[2] : u[4], o1i = hl ? u[3] : u[5];
  if constexpr (LM != 0) {
    float tr[4], ti[4];
    #pragma unroll
    for (int s = 0; s < 4; ++s) {
      tr[s] = __shfl_xor(pr[s ^ SM], LM);
      ti[s] = __shfl_xor(pi[s ^ SM], LM);
    }
    #pragma unroll
    for (int s = 0; s < 4; ++s) {
      const bool c1 = cpar(s & SR);
      const float dr = c1 ? d1r : d0r, di = c1 ? d1i : d0i;
      const float orr = c1 ? o1r : o0r, oi = c1 ? o1i : o0i;
      float ar = pr[s], ai = pi[s];
      pr[s] = dr*ar - di*ai + orr*tr[s] - oi*ti[s];
      pi[s] = dr*ai + di*ar + orr*ti[s] + oi*tr[s];
    }
  } else {
    constexpr int LOW = SM & (-SM);
    #pragma unroll
    for (int s = 0; s < 4; ++s) if (!(s & LOW)) {
      const int s1 = s ^ SM;
      const bool c1 = cpar(s & SR);
      const float dAr = c1 ? d1r : d0r, dAi = c1 ? d1i : d0i;
      const float oAr = c1 ? o1r : o0r, oAi = c1 ? o1i : o0i;
      const float dBr = c1 ? d0r : d1r, dBi = c1 ? d0i : d1i;
      const float oBr = c1 ? o0r : o1r, oBi = c1 ? o0i : o1i;
      float ar = pr[s], ai = pi[s], br = pr[s1], bi = pi[s1];
      pr[s]  = dAr*ar - dAi*ai + oAr*br - oAi*bi;
      pi[s]  = dAr*ai + dAi*ar + oAr*bi + oAi*br;
      pr[s1] = dBr*br - dBi*bi + oBr*ar - oBi*ai;
      pi[s1] = dBr*bi + dBi*br + oBr*ai + oBi*ar;
    }
  }
}

// ---- CRX, NEW-basis masks -------------------------------------------------
template<int LMt, int SMt, int LRc, int SRc>
DEV void crx_g(float* pr, float* pi, float c, float s_, int lane) {
  const bool hl = lpar(lane, LRc);
  const float cc0 = hl ? c : 1.0f, ss0 = hl ? s_ : 0.0f;
  const float cc1 = hl ? 1.0f : c, ss1 = hl ? 0.0f : s_;
  if constexpr (LMt != 0) {
    float tr[4], ti[4];
    #pragma unroll
    for (int s = 0; s < 4; ++s) {
      tr[s] = __shfl_xor(pr[s ^ SMt], LMt);
      ti[s] = __shfl_xor(pi[s ^ SMt], LMt);
    }
    #pragma unroll
    for (int s = 0; s < 4; ++s) {
      const bool c1 = cpar(s & SRc);
      const float cc = c1 ? cc1 : cc0, ss = c1 ? ss1 : ss0;
      float ar = pr[s], ai = pi[s];
      pr[s] = cc * ar + ss * ti[s];
      pi[s] = cc * ai - ss * tr[s];
    }
  } else {
    constexpr int LOW = SMt & (-SMt);
    #pragma unroll
    for (int s = 0; s < 4; ++s) if (!(s & LOW)) {
      const int s1 = s ^ SMt;
      const bool c1 = cpar(s & SRc);
      const float cc = c1 ? cc1 : cc0, ss = c1 ? ss1 : ss0;
      float ar = pr[s], ai = pi[s], br = pr[s1], bi = pi[s1];
      pr[s]  = cc * ar + ss * bi;
      pi[s]  = cc * ai - ss * br;
      pr[s1] = cc * br + ss * ai;
      pi[s1] = cc * bi - ss * ar;
    }
  }
}

// ---- U4 (fused entangler), NEW-basis masks --------------------------------
#define U4CLASS(Q)                                                            \
  if constexpr (!(((SRc == 0) && (Q & 2)) || ((SRt == 0) && (Q & 1)))) {      \
    const int r1 = R ^ Q, r2 = r1 ^ 2;                                        \
    const float2 wd = w2[r1 * 4 + r1],       wo = w2[r1 * 4 + (r1 ^ 1)];      \
    const float2 vd = w2[r2 * 4 + r1],       vo = w2[r2 * 4 + (r1 ^ 1)];      \
    _Pragma("unroll")                                                         \
    for (int s = 0; s < 4; ++s)                                               \
      if (((cpar(s & SRc) << 1) | cpar(s & SRt)) == Q) {                      \
        float ar = pr[s], ai = pi[s], br = tr[s], bi = ti[s];                 \
        pr[s] = wd.x*ar - wd.y*ai + wo.x*br - wo.y*bi;                        \
        pi[s] = wd.x*ai + wd.y*ar + wo.x*bi + wo.y*br;                        \
        tr[s] = vd.x*ar - vd.y*ai + vo.x*br - vo.y*bi;                        \
        ti[s] = vd.x*ai + vd.y*ar + vo.x*bi + vo.y*br;                        \
      }                                                                       \
  }

template<int LMc, int SMc, int LMt, int SMt, int LRc, int SRc, int LRt, int SRt>
DEV void u4_g(float* pr, float* pi, const float2* w2, int lane) {
  const int R = (lpar(lane, LRc) << 1) | lpar(lane, LRt);
  float tr[4], ti[4];
  #pragma unroll
  for (int s = 0; s < 4; ++s) {
    float vr = pr[s ^ SMt], vi = pi[s ^ SMt];
    if constexpr (LMt != 0) { vr = __shfl_xor(vr, LMt); vi = __shfl_xor(vi, LMt); }
    tr[s] = vr; ti[s] = vi;
  }
  U4CLASS(0) U4CLASS(1) U4CLASS(2) U4CLASS(3)
  #pragma unroll
  for (int s = 0; s < 4; ++s) {
    float br = tr[s ^ SMc], bi = ti[s ^ SMc];
    if constexpr (LMc != 0) { br = __shfl_xor(br, LMc); bi = __shfl_xor(bi, LMc); }
    pr[s] += br; pi[s] += bi;
  }
}

// ---- OLD-basis wrappers: keep the verified R5/R6 mask tables verbatim -----
template<int LMc,int SMc,int LMt,int SMt,int LRc,int SRc,int LRt,int SRt>
DEV void u4o(float* pr, float* pi, const float2* w2, int lane) {
  u4_g<TLm(LMc,SMc),TSm(SMc), TLm(LMt,SMt),TSm(SMt),
       TLm(LRc,SRc),TSm(SRc), TLm(LRt,SRt),TSm(SRt)>(pr, pi, w2, lane);
}
template<int LM,int SM,int LR,int SR>
DEV void u3o(float* pr, float* pi, const float* u, int lane) {
  u3_g<TLm(LM,SM),TSm(SM), TLm(LR,SR),TSm(SR)>(pr, pi, u, lane);
}
template<int LMt,int SMt,int LRc,int SRc>
DEV void crxo(float* pr, float* pi, float c, float s_, int lane) {
  crx_g<TLm(LMt,SMt),TSm(SMt), TLm(LRc,SRc),TSm(SRc)>(pr, pi, c, s_, lane);
}

// ---- U3 coefficient build -------------------------------------------------
DEV void u3_make(float t, float p, float l, float* u) {
  float c = __cosf(0.5f * t), s = __sinf(0.5f * t);
  float cp = __cosf(p), sp = __sinf(p);
  float cl = __cosf(l), sl = __sinf(l);
  float cpl = __cosf(p + l), spl = __sinf(p + l);
  u[0] = c;        u[1] = 0.0f;
  u[2] = -cl * s;  u[3] = -sl * s;
  u[4] = cp * s;   u[5] = sp * s;
  u[6] = cpl * c;  u[7] = spl * c;
}

// ---- <Z3>,<Z7>: old (LR=10,SR=1)/(10,0) -> new lane mask 40, s bit0 -------
DEV void expz_fin(const float* pr, const float* pi, int lane, float& z3, float& z7) {
  float t3 = 0.0f, t7 = 0.0f;
  #pragma unroll
  for (int s = 0; s < 4; ++s) {
    float p = pr[s] * pr[s] + pi[s] * pi[s];
    t7 += p;
    t3 += (s & 1) ? -p : p;
  }
  if (lpar(lane, 40)) { t3 = -t3; t7 = -t7; }
  #pragma unroll
  for (int m = 1; m < 64; m <<= 1) {
    t3 += __shfl_xor(t3, m);
    t7 += __shfl_xor(t7, m);
  }
  z3 = t3; z7 = t7;
}

// ---------------------------------------------------------------------------

__global__ __launch_bounds__(1024, 4)
void qcnn_kernel(const float* __restrict__ x,
                 const float* __restrict__ rz_p, const float* __restrict__ ry_p,
                 const float* __restrict__ ry2_p, const float* __restrict__ crx_p,
                 const float* __restrict__ u3_p, const float* __restrict__ u3b_p,
                 const float* __restrict__ W1, const float* __restrict__ b1,
                 const float* __restrict__ W2, const float* __restrict__ b2,
                 float* __restrict__ out, int B) {
  __shared__ __align__(8) float cw[64];       // 2 layers x 16 complex fused-U4

  const int tid  = threadIdx.x;
  const int lane = tid & 63;
  const int wave = tid >> 6;                   // 0..15
  const int sub  = lane & 15;
  const int elem  = blockIdx.x * 16 + wave;    // 1 element per wave
  const int elemc = elem < B ? elem : (B - 1);

  // ---- fused U4 build (wave 0, lanes 0..31; one complex entry per lane) ---
  if (tid < 32) {
    const int lay = tid >> 4, e = tid & 15, i4 = e >> 2, j4 = e & 3;
    const int base = tid & 48;
    const float c45 = 0.70710678118654752f;
    float rz = rz_p[lay], ry = ry_p[lay], ry2 = ry2_p[lay];
    float mr = (i4 == j4) ? c45 : 0.0f;
    float mi = (i4 == j4) ? ((i4 & 1) ? -c45 : c45) : 0.0f;
    { int t = (i4 & 1) ? (i4 ^ 2) : i4; int src = base | (t << 2) | j4;
      mr = __shfl(mr, src); mi = __shfl(mi, src); }
    { float cz = __cosf(0.5f * rz), sz = __sinf(0.5f * rz);
      float di = (i4 & 2) ? sz : -sz;
      float nr = cz * mr - di * mi, ni = cz * mi + di * mr; mr = nr; mi = ni; }
    { float cy = __cosf(0.5f * ry), sy = __sinf(0.5f * ry);
      int src = base | ((i4 ^ 1) << 2) | j4;
      float orr = __shfl(mr, src), oii = __shfl(mi, src);
      float sg = (i4 & 1) ? sy : -sy;
      mr = cy * mr + sg * orr; mi = cy * mi + sg * oii; }
    { int t = (i4 & 2) ? (i4 ^ 1) : i4; int src = base | (t << 2) | j4;
      mr = __shfl(mr, src); mi = __shfl(mi, src); }
    { float cy = __cosf(0.5f * ry2), sy = __sinf(0.5f * ry2);
      int src = base | ((i4 ^ 1) << 2) | j4;
      float orr = __shfl(mr, src), oii = __shfl(mi, src);
      float sg = (i4 & 1) ? sy : -sy;
      mr = cy * mr + sg * orr; mi = cy * mi + sg * oii; }
    { int t = (i4 & 1) ? (i4 ^ 2) : i4; int src = base | (t << 2) | j4;
      mr = __shfl(mr, src); mi = __shfl(mi, src); }
    { float di = (i4 & 2) ? c45 : -c45;
      float nr = c45 * mr - di * mi, ni = c45 * mi + di * mr; mr = nr; mi = ni; }
    cw[(lay * 16 + e) * 2]     = mr;
    cw[(lay * 16 + e) * 2 + 1] = mi;
  }

  // ---- angles: lane sub (= lane&15) holds angles 2*sub, 2*sub+1; the pair
  // is replicated 4x across the wave (1 element/wave). Broadcast via __shfl
  // from lane k>>1 (< 16).
  float2 aa = ((const float2*)x)[(size_t)elemc * 16 + sub];
  float ch0 = __cosf(0.5f * aa.x), sh0 = __sinf(0.5f * aa.x);
  float ch1 = __cosf(0.5f * aa.y), sh1 = __sinf(0.5f * aa.y);

  float cq[8], sq[8];
  #pragma unroll
  for (int q = 0; q < 8; ++q) {
    cq[q] = __shfl((q & 1) ? ch1 : ch0, q >> 1);
    sq[q] = __shfl((q & 1) ? sh1 : sh0, q >> 1);
  }

  // ---- product-state init (cycle-1 RYs; state real) -----------------------
  // New lane bits (5..0): q0 q2 q4 q6 q1 q3 ; s bits (1..0): q5 q7
  float p[4];
  {
    float g = ((lane & 32) ? sq[0] : cq[0]) * ((lane & 16) ? sq[2] : cq[2]) *
              ((lane & 8)  ? sq[4] : cq[4]) * ((lane & 4)  ? sq[6] : cq[6]) *
              ((lane & 2)  ? sq[1] : cq[1]) * ((lane & 1)  ? sq[3] : cq[3]);
    p[0] = g * cq[5] * cq[7];
    p[1] = g * cq[5] * sq[7];
    p[2] = g * sq[5] * cq[7];
    p[3] = g * sq[5] * sq[7];
  }

  // ---- encode cycles 2..4 (24 real RYs; OLD masks, transformed inline) ----
  #define ENC(k, LM, SM, LR, SR) {                                  \
    float gc = __shfl(((k) & 1) ? ch1 : ch0, (k) >> 1);             \
    float gs = __shfl(((k) & 1) ? sh1 : sh0, (k) >> 1);             \
    ryr<TLm(LM,SM), TSm(SM), TLm(LR,SR), TSm(SR)>(p, gc, gs, lane); }

  ENC(8,  8,8, 7,15)  ENC(9,  4,8, 8,8)   ENC(10, 4,4, 12,8)  ENC(11, 2,4, 12,12)
  ENC(12, 2,2, 14,12) ENC(13, 1,2, 14,14) ENC(14, 1,1, 15,14) ENC(15, 8,9, 15,15)
  ENC(16, 12,0, 8,15) ENC(17, 0,12, 15,7) ENC(18, 6,0, 3,15)  ENC(19, 0,6, 15,3)
  ENC(20, 3,0, 1,15)  ENC(21, 0,3, 15,1)  ENC(22, 9,8, 0,15)  ENC(23, 4,9, 15,0)
  ENC(24, 12,12, 2,10) ENC(25, 6,12, 7,8) ENC(26, 6,6, 4,7)   ENC(27, 3,6, 11,4)
  ENC(28, 3,3, 10,11)  ENC(29, 9,11, 5,10) ENC(30, 13,1, 5,5) ENC(31, 8,5, 10,5)
  #undef ENC

  // ---- park real encode state in 4 registers for psi1 ---------------------
  const float e0 = p[0], e1 = p[1], e2_ = p[2], e3 = p[3];

  __syncthreads();  // cw ready
  const float2* w0 = (const float2*)cw;
  const float2* w1 = ((const float2*)cw) + 16;

  // ---- psi0: conv layers --------------------------------------------------
  float pi_[4] = {0.0f, 0.0f, 0.0f, 0.0f};

  u4o<10,0,  0,10, 8,10, 5,2 >(p, pi_, w0, lane);   // (0,1)
  u4o<5,0,   0,5,  1,5,  10,1>(p, pi_, w0, lane);   // (2,3)
  u4o<10,8,  4,10, 0,10, 5,0 >(p, pi_, w0, lane);   // (4,5)
  u4o<5,4,   2,5,  0,5,  10,0>(p, pi_, w0, lane);   // (6,7)
  u4o<0,10,  5,0,  5,2,  1,5 >(p, pi_, w0, lane);   // (1,2)
  u4o<0,5,   10,8, 10,1, 0,10>(p, pi_, w0, lane);   // (3,4)
  u4o<4,10,  5,4,  5,0,  0,5 >(p, pi_, w0, lane);   // (5,6)
  {
    float ua[8]; u3_make(u3_p[0], u3_p[1], u3_p[2], ua);
    u3o<0,10, 5,2 >(p, pi_, ua, lane);   // q1
    u3o<0,5,  10,1>(p, pi_, ua, lane);   // q3
    u3o<4,10, 5,0 >(p, pi_, ua, lane);   // q5
    u3o<2,5,  10,0>(p, pi_, ua, lane);   // q7
  }
  u4o<0,10,  0,5,  5,2,  10,1>(p, pi_, w1, lane);   // (1,3)
  u4o<4,10,  2,5,  5,0,  10,0>(p, pi_, w1, lane);   // (5,7)
  u4o<0,5,   4,10, 10,1, 5,0 >(p, pi_, w1, lane);   // (3,5)
  {
    float ua[8]; u3_make(u3_p[3], u3_p[4], u3_p[5], ua);
    u3o<0,5,  10,1>(p, pi_, ua, lane);   // q3
    u3o<2,5,  10,0>(p, pi_, ua, lane);   // q7
  }

  float f0, f1;
  expz_fin(p, pi_, lane, f0, f1);

  // ---- psi1: restore enc from registers, CRX ladders + U3b ----------------
  p[0] = e0; p[1] = e1; p[2] = e2_; p[3] = e3;
  pi_[0] = 0.0f; pi_[1] = 0.0f; pi_[2] = 0.0f; pi_[3] = 0.0f;

  {
    float t = crx_p[0];
    float cc = __cosf(0.5f * t), ss = __sinf(0.5f * t);
    crxo<0,10, 8,10>(p, pi_, cc, ss, lane);   // (0,1)
    crxo<0,5,  1,5 >(p, pi_, cc, ss, lane);   // (2,3)
    crxo<4,10, 0,10>(p, pi_, cc, ss, lane);   // (4,5)
    crxo<2,5,  0,5 >(p, pi_, cc, ss, lane);   // (6,7)
    crxo<5,0,  5,2 >(p, pi_, cc, ss, lane);   // (1,2)
    crxo<10,8, 10,1>(p, pi_, cc, ss, lane);   // (3,4)
    crxo<5,4,  5,0 >(p, pi_, cc, ss, lane);   // (5,6)
  }
  {
    float ub[8]; u3_make(u3b_p[0], u3b_p[1], u3b_p[2], ub);
    u3o<0,10, 5,2 >(p, pi_, ub, lane);
    u3o<0,5,  10,1>(p, pi_, ub, lane);
    u3o<4,10, 5,0 >(p, pi_, ub, lane);
    u3o<2,5,  10,0>(p, pi_, ub, lane);
  }
  {
    float t = crx_p[1];
    float cc = __cosf(0.5f * t), ss = __sinf(0.5f * t);
    crxo<0,5,  5,2 >(p, pi_, cc, ss, lane);   // (1,3)
    crxo<2,5,  5,0 >(p, pi_, cc, ss, lane);   // (5,7)
    crxo<4,10, 10,1>(p, pi_, cc, ss, lane);   // (3,5)
  }
  {
    float ub[8]; u3_make(u3b_p[3], u3b_p[4], u3b_p[5], ub);
    u3o<0,5,  10,1>(p, pi_, ub, lane);
    u3o<2,5,  10,0>(p, pi_, ub, lane);
  }

  float f2, f3;
  expz_fin(p, pi_, lane, f2, f3);

  // ---- MLP (whole wave = one element) -------------------------------------
  const int j = (lane < 15) ? lane : 0;
  float acc = W1[j * 4 + 0] * f0 + W1[j * 4 + 1] * f1 +
              W1[j * 4 + 2] * f2 + W1[j * 4 + 3] * f3 + b1[j];
  float e2 = __expf(2.0f * acc);
  float th = (e2 - 1.0f) / (e2 + 1.0f);
  float part = (lane < 15) ? th * W2[j] : 0.0f;
  #pragma unroll
  for (int m = 1; m < 64; m <<= 1) part += __shfl_xor(part, m);

  if (lane == 0 && elem < B) {
    float z = part + b2[0];
    out[elem] = 1.0f / (1.0f + __expf(-z));
  }
}

extern "C" void kernel_launch(void* const* d_in, const int* in_sizes, int n_in,
                              void* d_out, int out_size, void* d_ws, size_t ws_size,
                              hipStream_t stream) {
  (void)n_in; (void)out_size; (void)d_ws; (void)ws_size;
  const float* x     = (const float*)d_in[0];
  const float* rz_p  = (const float*)d_in[1];
  const float* ry_p  = (const float*)d_in[2];
  const float* ry2_p = (const float*)d_in[3];
  const float* crx_p = (const float*)d_in[4];
  const float* u3_p  = (const float*)d_in[5];
  const float* u3b_p = (const float*)d_in[6];
  const float* W1    = (const float*)d_in[7];
  const float* b1    = (const float*)d_in[8];
  const float* W2    = (const float*)d_in[9];
  const float* b2    = (const float*)d_in[10];
  float* out = (float*)d_out;

  const int B = in_sizes[0] / 32;          // 8192
  const int blocks = (B + 15) / 16;        // 1 elem/wave, 16 waves/block -> 512
  qcnn_kernel<<<dim3(blocks), dim3(1024), 0, stream>>>(
      x, rz_p, ry_p, ry2_p, crx_p, u3_p, u3b_p, W1, b1, W2, b2, out, B);
}

// Round 6
// 119.465 us; speedup vs baseline: 3.4079x; 1.0513x over previous
//
#include <hip/hip_runtime.h>

#define DEV __device__ __forceinline__

// ---------------------------------------------------------------------------
// R12: 32 lanes/elem x 8 amps/lane — TWO elements per wave in parallel
// lane-halves (lane<32 / lane>=32). 4096 waves, 512 blocks x 512 threads.
//   Why: graded-minus-dispatch gap tracks TOTAL WAVE COUNT across R6-R11
//   (2048w->~8us, 4096w->~20us, 8192w->~65us), not blocks/threads/LDS/VGPR.
//   R11 (512 blocks, 8192 waves) killed the block-count theory: clean 62us
//   dispatch, graded 125.6. This halves waves to 4096 with NO serial loop
//   (R10's spill trap) and NO fat 16-amp waves (R6's latency trap).
//   Straight-line body identical in structure to the verified R9 island.
//   __launch_bounds__(512, 2): the (x,2) family is the only bound that has
//   produced sane allocations for big live sets (R1/R5 lore); avoids the
//   64-VGPR squeeze-spill tier that killed R8/R10.
//
// Basis: element = lane>>5. Within half: lane5 bits 4..0 = q0 q2 q4 q6 q1,
// s3 bits 2..0 = q3 q5 q7. Old-basis mask tables (verified R5/R6) kept
// VERBATIM; compile-time transform: LM' = (LM<<1)|(SM>>3), SM' = SM&7
// (same for parity masks). All transformed lane masks < 32 => halves never
// interact via __shfl_xor. Broadcasts use src = (lane&32)|k.
// expz: old (LR=10,SR=1)/(10,0) -> lane mask 20, s bit0; butterfly m=1..16.
// ---------------------------------------------------------------------------

DEV int lpar(int lane, int m) { return __builtin_popcount(lane & m) & 1; }
constexpr int cpar(int v) { return (v ^ (v >> 1) ^ (v >> 2) ^ (v >> 3)) & 1; }

// compile-time basis transform: old (mask-over-L4, mask-over-S4) -> new
constexpr int TLm(int LM, int SM) { return (LM << 1) | (SM >> 3); }  // lane5 mask
constexpr int TSm(int SM) { return SM & 7; }                         // s3 mask

// ---- real RY, NEW-basis masks (8 amps/lane) -------------------------------
template<int LM, int SM, int LR, int SR>
DEV void ryr(float* p, float gc, float gs, int lane) {
  const float sg0 = lpar(lane, LR) ? gs : -gs;   // sign when cpar(s&SR)==0
  const float sg1 = -sg0;
  if constexpr (LM != 0) {
    float t[8];
    #pragma unroll
    for (int s = 0; s < 8; ++s) t[s] = __shfl_xor(p[s ^ SM], LM);
    #pragma unroll
    for (int s = 0; s < 8; ++s)
      p[s] = gc * p[s] + (cpar(s & SR) ? sg1 : sg0) * t[s];
  } else {
    constexpr int LOW = SM & (-SM);
    #pragma unroll
    for (int s = 0; s < 8; ++s) if (!(s & LOW)) {
      const int s1 = s ^ SM;
      float a = p[s], b = p[s1];
      float sg = cpar(s & SR) ? sg1 : sg0;
      p[s]  = gc * a + sg * b;
      p[s1] = gc * b - sg * a;
    }
  }
}

// ---- complex U3, NEW-basis masks ------------------------------------------
template<int LM, int SM, int LR, int SR>
DEV void u3_g(float* pr, float* pi, const float* u, int lane) {
  const bool hl = lpar(lane, LR);
  const float d0r = hl ? u[6] : u[0], d0i = hl ? u[7] : u[1];
  const float o0r = hl ? u[4] : u[2], o0i = hl ? u[5] : u[3];
  const float d1r = hl ? u[0] : u[6], d1i = hl ? u[1] : u[7];
  const float o1r = hl ? u[2] : u[4], o1i = hl ? u[3] : u[5];
  if constexpr (LM != 0) {
    float tr[8], ti[8];
    #pragma unroll
    for (int s = 0; s < 8; ++s) {
      tr[s] = __shfl_xor(pr[s ^ SM], LM);
      ti[s] = __shfl_xor(pi[s ^ SM], LM);
    }
    #pragma unroll
    for (int s = 0; s < 8; ++s) {
      const bool c1 = cpar(s & SR);
      const float dr = c1 ? d1r : d0r, di = c1 ? d1i : d0i;
      const float orr = c1 ? o1r : o0r, oi = c1 ? o1i : o0i;
      float ar = pr[s], ai = pi[s];
      pr[s] = dr*ar - di*ai + orr*tr[s] - oi*ti[s];
      pi[s] = dr*ai + di*ar + orr*ti[s] + oi*tr[s];
    }
  } else {
    constexpr int LOW = SM & (-SM);
    #pragma unroll
    for (int s = 0; s < 8; ++s) if (!(s & LOW)) {
      const int s1 = s ^ SM;
      const bool c1 = cpar(s & SR);
      const float dAr = c1 ? d1r : d0r, dAi = c1 ? d1i : d0i;
      const float oAr = c1 ? o1r : o0r, oAi = c1 ? o1i : o0i;
      const float dBr = c1 ? d0r : d1r, dBi = c1 ? d0i : d1i;
      const float oBr = c1 ? o0r : o1r, oBi = c1 ? o0i : o1i;
      float ar = pr[s], ai = pi[s], br = pr[s1], bi = pi[s1];
      pr[s]  = dAr*ar - dAi*ai + oAr*br - oAi*bi;
      pi[s]  = dAr*ai + dAi*ar + oAr*bi + oAi*br;
      pr[s1] = dBr*br - dBi*bi + oBr*ar - oBi*ai;
      pi[s1] = dBr*bi + dBi*br + oBr*ai + oBi*ar;
    }
  }
}

// ---- CRX, NEW-basis masks -------------------------------------------------
template<int LMt, int SMt, int LRc, int SRc>
DEV void crx_g(float* pr, float* pi, float c, float s_, int lane) {
  const bool hl = lpar(lane, LRc);
  const float cc0 = hl ? c : 1.0f, ss0 = hl ? s_ : 0.0f;
  const float cc1 = hl ? 1.0f : c, ss1 = hl ? 0.0f : s_;
  if constexpr (LMt != 0) {
    float tr[8], ti[8];
    #pragma unroll
    for (int s = 0; s < 8; ++s) {
      tr[s] = __shfl_xor(pr[s ^ SMt], LMt);
      ti[s] = __shfl_xor(pi[s ^ SMt], LMt);
    }
    #pragma unroll
    for (int s = 0; s < 8; ++s) {
      const bool c1 = cpar(s & SRc);
      const float cc = c1 ? cc1 : cc0, ss = c1 ? ss1 : ss0;
      float ar = pr[s], ai = pi[s];
      pr[s] = cc * ar + ss * ti[s];
      pi[s] = cc * ai - ss * tr[s];
    }
  } else {
    constexpr int LOW = SMt & (-SMt);
    #pragma unroll
    for (int s = 0; s < 8; ++s) if (!(s & LOW)) {
      const int s1 = s ^ SMt;
      const bool c1 = cpar(s & SRc);
      const float cc = c1 ? cc1 : cc0, ss = c1 ? ss1 : ss0;
      float ar = pr[s], ai = pi[s], br = pr[s1], bi = pi[s1];
      pr[s]  = cc * ar + ss * bi;
      pi[s]  = cc * ai - ss * br;
      pr[s1] = cc * br + ss * ai;
      pi[s1] = cc * bi - ss * ar;
    }
  }
}

// ---- U4 (fused entangler), NEW-basis masks --------------------------------
#define U4CLASS(Q)                                                            \
  if constexpr (!(((SRc == 0) && (Q & 2)) || ((SRt == 0) && (Q & 1)))) {      \
    const int r1 = R ^ Q, r2 = r1 ^ 2;                                        \
    const float2 wd = w2[r1 * 4 + r1],       wo = w2[r1 * 4 + (r1 ^ 1)];      \
    const float2 vd = w2[r2 * 4 + r1],       vo = w2[r2 * 4 + (r1 ^ 1)];      \
    _Pragma("unroll")                                                         \
    for (int s = 0; s < 8; ++s)                                               \
      if (((cpar(s & SRc) << 1) | cpar(s & SRt)) == Q) {                      \
        float ar = pr[s], ai = pi[s], br = tr[s], bi = ti[s];                 \
        pr[s] = wd.x*ar - wd.y*ai + wo.x*br - wo.y*bi;                        \
        pi[s] = wd.x*ai + wd.y*ar + wo.x*bi + wo.y*br;                        \
        tr[s] = vd.x*ar - vd.y*ai + vo.x*br - vo.y*bi;                        \
        ti[s] = vd.x*ai + vd.y*ar + vo.x*bi + vo.y*br;                        \
      }                                                                       \
  }

template<int LMc, int SMc, int LMt, int SMt, int LRc, int SRc, int LRt, int SRt>
DEV void u4_g(float* pr, float* pi, const float2* w2, int lane) {
  const int R = (lpar(lane, LRc) << 1) | lpar(lane, LRt);
  float tr[8], ti[8];
  #pragma unroll
  for (int s = 0; s < 8; ++s) {
    float vr = pr[s ^ SMt], vi = pi[s ^ SMt];
    if constexpr (LMt != 0) { vr = __shfl_xor(vr, LMt); vi = __shfl_xor(vi, LMt); }
    tr[s] = vr; ti[s] = vi;
  }
  U4CLASS(0) U4CLASS(1) U4CLASS(2) U4CLASS(3)
  #pragma unroll
  for (int s = 0; s < 8; ++s) {
    float br = tr[s ^ SMc], bi = ti[s ^ SMc];
    if constexpr (LMc != 0) { br = __shfl_xor(br, LMc); bi = __shfl_xor(bi, LMc); }
    pr[s] += br; pi[s] += bi;
  }
}

// ---- OLD-basis wrappers: keep the verified R5/R6 mask tables verbatim -----
template<int LMc,int SMc,int LMt,int SMt,int LRc,int SRc,int LRt,int SRt>
DEV void u4o(float* pr, float* pi, const float2* w2, int lane) {
  u4_g<TLm(LMc,SMc),TSm(SMc), TLm(LMt,SMt),TSm(SMt),
       TLm(LRc,SRc),TSm(SRc), TLm(LRt,SRt),TSm(SRt)>(pr, pi, w2, lane);
}
template<int LM,int SM,int LR,int SR>
DEV void u3o(float* pr, float* pi, const float* u, int lane) {
  u3_g<TLm(LM,SM),TSm(SM), TLm(LR,SR),TSm(SR)>(pr, pi, u, lane);
}
template<int LMt,int SMt,int LRc,int SRc>
DEV void crxo(float* pr, float* pi, float c, float s_, int lane) {
  crx_g<TLm(LMt,SMt),TSm(SMt), TLm(LRc,SRc),TSm(SRc)>(pr, pi, c, s_, lane);
}

// ---- U3 coefficient build -------------------------------------------------
DEV void u3_make(float t, float p, float l, float* u) {
  float c = __cosf(0.5f * t), s = __sinf(0.5f * t);
  float cp = __cosf(p), sp = __sinf(p);
  float cl = __cosf(l), sl = __sinf(l);
  float cpl = __cosf(p + l), spl = __sinf(p + l);
  u[0] = c;        u[1] = 0.0f;
  u[2] = -cl * s;  u[3] = -sl * s;
  u[4] = cp * s;   u[5] = sp * s;
  u[6] = cpl * c;  u[7] = spl * c;
}

// ---- <Z3>,<Z7>: old (LR=10,SR=1)/(10,0) -> lane mask 20, s bit0 -----------
// Per-half reduction: butterfly m=1..16 only (halves independent).
DEV void expz_fin(const float* pr, const float* pi, int lane, float& z3, float& z7) {
  float t3 = 0.0f, t7 = 0.0f;
  #pragma unroll
  for (int s = 0; s < 8; ++s) {
    float p = pr[s] * pr[s] + pi[s] * pi[s];
    t7 += p;
    t3 += (s & 1) ? -p : p;
  }
  if (lpar(lane, 20)) { t3 = -t3; t7 = -t7; }
  #pragma unroll
  for (int m = 1; m < 32; m <<= 1) {
    t3 += __shfl_xor(t3, m);
    t7 += __shfl_xor(t7, m);
  }
  z3 = t3; z7 = t7;
}

// ---------------------------------------------------------------------------

__global__ __launch_bounds__(512, 2)
void qcnn_kernel(const float* __restrict__ x,
                 const float* __restrict__ rz_p, const float* __restrict__ ry_p,
                 const float* __restrict__ ry2_p, const float* __restrict__ crx_p,
                 const float* __restrict__ u3_p, const float* __restrict__ u3b_p,
                 const float* __restrict__ W1, const float* __restrict__ b1,
                 const float* __restrict__ W2, const float* __restrict__ b2,
                 float* __restrict__ out, int B) {
  __shared__ __align__(8) float cw[64];       // 2 layers x 16 complex fused-U4

  const int tid  = threadIdx.x;
  const int lane = tid & 63;
  const int wave = tid >> 6;                   // 0..7
  const int sub  = lane & 15;
  const int half = lane >> 5;                  // element index within wave
  const int l5   = lane & 31;
  const int hb   = lane & 32;
  const int elem  = blockIdx.x * 16 + wave * 2 + half;  // 2 elems/wave
  const int elemc = elem < B ? elem : (B - 1);

  // ---- fused U4 build (wave 0, lanes 0..31; one complex entry per lane) ---
  if (tid < 32) {
    const int lay = tid >> 4, e = tid & 15, i4 = e >> 2, j4 = e & 3;
    const int base = tid & 48;
    const float c45 = 0.70710678118654752f;
    float rz = rz_p[lay], ry = ry_p[lay], ry2 = ry2_p[lay];
    float mr = (i4 == j4) ? c45 : 0.0f;
    float mi = (i4 == j4) ? ((i4 & 1) ? -c45 : c45) : 0.0f;
    { int t = (i4 & 1) ? (i4 ^ 2) : i4; int src = base | (t << 2) | j4;
      mr = __shfl(mr, src); mi = __shfl(mi, src); }
    { float cz = __cosf(0.5f * rz), sz = __sinf(0.5f * rz);
      float di = (i4 & 2) ? sz : -sz;
      float nr = cz * mr - di * mi, ni = cz * mi + di * mr; mr = nr; mi = ni; }
    { float cy = __cosf(0.5f * ry), sy = __sinf(0.5f * ry);
      int src = base | ((i4 ^ 1) << 2) | j4;
      float orr = __shfl(mr, src), oii = __shfl(mi, src);
      float sg = (i4 & 1) ? sy : -sy;
      mr = cy * mr + sg * orr; mi = cy * mi + sg * oii; }
    { int t = (i4 & 2) ? (i4 ^ 1) : i4; int src = base | (t << 2) | j4;
      mr = __shfl(mr, src); mi = __shfl(mi, src); }
    { float cy = __cosf(0.5f * ry2), sy = __sinf(0.5f * ry2);
      int src = base | ((i4 ^ 1) << 2) | j4;
      float orr = __shfl(mr, src), oii = __shfl(mi, src);
      float sg = (i4 & 1) ? sy : -sy;
      mr = cy * mr + sg * orr; mi = cy * mi + sg * oii; }
    { int t = (i4 & 1) ? (i4 ^ 2) : i4; int src = base | (t << 2) | j4;
      mr = __shfl(mr, src); mi = __shfl(mi, src); }
    { float di = (i4 & 2) ? c45 : -c45;
      float nr = c45 * mr - di * mi, ni = c45 * mi + di * mr; mr = nr; mi = ni; }
    cw[(lay * 16 + e) * 2]     = mr;
    cw[(lay * 16 + e) * 2 + 1] = mi;
  }

  // ---- angles: per half-wave, lane sub holds angles 2*sub, 2*sub+1 --------
  // (lanes 16..31 of each half hold redundant copies; broadcasts use hb|k.)
  float2 aa = ((const float2*)x)[(size_t)elemc * 16 + sub];
  float ch0 = __cosf(0.5f * aa.x), sh0 = __sinf(0.5f * aa.x);
  float ch1 = __cosf(0.5f * aa.y), sh1 = __sinf(0.5f * aa.y);

  float cq[8], sq[8];
  #pragma unroll
  for (int q = 0; q < 8; ++q) {
    cq[q] = __shfl((q & 1) ? ch1 : ch0, hb | (q >> 1));
    sq[q] = __shfl((q & 1) ? sh1 : sh0, hb | (q >> 1));
  }

  // ---- product-state init (cycle-1 RYs; state real) -----------------------
  // lane5 bits 4..0: q0 q2 q4 q6 q1 ; s3 bits 2..0: q3 q5 q7
  float p[8];
  {
    float g = ((l5 & 16) ? sq[0] : cq[0]) * ((l5 & 8) ? sq[2] : cq[2]) *
              ((l5 & 4)  ? sq[4] : cq[4]) * ((l5 & 2) ? sq[6] : cq[6]) *
              ((l5 & 1)  ? sq[1] : cq[1]);
    #pragma unroll
    for (int s = 0; s < 8; ++s)
      p[s] = g * ((s & 4) ? sq[3] : cq[3]) * ((s & 2) ? sq[5] : cq[5]) *
                 ((s & 1) ? sq[7] : cq[7]);
  }

  // ---- encode cycles 2..4 (24 real RYs; OLD masks, transformed inline) ----
  #define ENC(k, LM, SM, LR, SR) {                                  \
    float gc = __shfl(((k) & 1) ? ch1 : ch0, hb | ((k) >> 1));      \
    float gs = __shfl(((k) & 1) ? sh1 : sh0, hb | ((k) >> 1));      \
    ryr<TLm(LM,SM), TSm(SM), TLm(LR,SR), TSm(SR)>(p, gc, gs, lane); }

  ENC(8,  8,8, 7,15)  ENC(9,  4,8, 8,8)   ENC(10, 4,4, 12,8)  ENC(11, 2,4, 12,12)
  ENC(12, 2,2, 14,12) ENC(13, 1,2, 14,14) ENC(14, 1,1, 15,14) ENC(15, 8,9, 15,15)
  ENC(16, 12,0, 8,15) ENC(17, 0,12, 15,7) ENC(18, 6,0, 3,15)  ENC(19, 0,6, 15,3)
  ENC(20, 3,0, 1,15)  ENC(21, 0,3, 15,1)  ENC(22, 9,8, 0,15)  ENC(23, 4,9, 15,0)
  ENC(24, 12,12, 2,10) ENC(25, 6,12, 7,8) ENC(26, 6,6, 4,7)   ENC(27, 3,6, 11,4)
  ENC(28, 3,3, 10,11)  ENC(29, 9,11, 5,10) ENC(30, 13,1, 5,5) ENC(31, 8,5, 10,5)
  #undef ENC

  // ---- park real encode state in 8 registers for psi1 ---------------------
  float e_[8];
  #pragma unroll
  for (int s = 0; s < 8; ++s) e_[s] = p[s];

  __syncthreads();  // cw ready
  const float2* w0 = (const float2*)cw;
  const float2* w1 = ((const float2*)cw) + 16;

  // ---- psi0: conv layers --------------------------------------------------
  float pi_[8];
  #pragma unroll
  for (int s = 0; s < 8; ++s) pi_[s] = 0.0f;

  u4o<10,0,  0,10, 8,10, 5,2 >(p, pi_, w0, lane);   // (0,1)
  u4o<5,0,   0,5,  1,5,  10,1>(p, pi_, w0, lane);   // (2,3)
  u4o<10,8,  4,10, 0,10, 5,0 >(p, pi_, w0, lane);   // (4,5)
  u4o<5,4,   2,5,  0,5,  10,0>(p, pi_, w0, lane);   // (6,7)
  u4o<0,10,  5,0,  5,2,  1,5 >(p, pi_, w0, lane);   // (1,2)
  u4o<0,5,   10,8, 10,1, 0,10>(p, pi_, w0, lane);   // (3,4)
  u4o<4,10,  5,4,  5,0,  0,5 >(p, pi_, w0, lane);   // (5,6)
  {
    float ua[8]; u3_make(u3_p[0], u3_p[1], u3_p[2], ua);
    u3o<0,10, 5,2 >(p, pi_, ua, lane);   // q1
    u3o<0,5,  10,1>(p, pi_, ua, lane);   // q3
    u3o<4,10, 5,0 >(p, pi_, ua, lane);   // q5
    u3o<2,5,  10,0>(p, pi_, ua, lane);   // q7
  }
  u4o<0,10,  0,5,  5,2,  10,1>(p, pi_, w1, lane);   // (1,3)
  u4o<4,10,  2,5,  5,0,  10,0>(p, pi_, w1, lane);   // (5,7)
  u4o<0,5,   4,10, 10,1, 5,0 >(p, pi_, w1, lane);   // (3,5)
  {
    float ua[8]; u3_make(u3_p[3], u3_p[4], u3_p[5], ua);
    u3o<0,5,  10,1>(p, pi_, ua, lane);   // q3
    u3o<2,5,  10,0>(p, pi_, ua, lane);   // q7
  }

  float f0, f1;
  expz_fin(p, pi_, lane, f0, f1);

  // ---- psi1: restore enc from registers, CRX ladders + U3b ----------------
  #pragma unroll
  for (int s = 0; s < 8; ++s) { p[s] = e_[s]; pi_[s] = 0.0f; }

  {
    float t = crx_p[0];
    float cc = __cosf(0.5f * t), ss = __sinf(0.5f * t);
    crxo<0,10, 8,10>(p, pi_, cc, ss, lane);   // (0,1)
    crxo<0,5,  1,5 >(p, pi_, cc, ss, lane);   // (2,3)
    crxo<4,10, 0,10>(p, pi_, cc, ss, lane);   // (4,5)
    crxo<2,5,  0,5 >(p, pi_, cc, ss, lane);   // (6,7)
    crxo<5,0,  5,2 >(p, pi_, cc, ss, lane);   // (1,2)
    crxo<10,8, 10,1>(p, pi_, cc, ss, lane);   // (3,4)
    crxo<5,4,  5,0 >(p, pi_, cc, ss, lane);   // (5,6)
  }
  {
    float ub[8]; u3_make(u3b_p[0], u3b_p[1], u3b_p[2], ub);
    u3o<0,10, 5,2 >(p, pi_, ub, lane);
    u3o<0,5,  10,1>(p, pi_, ub, lane);
    u3o<4,10, 5,0 >(p, pi_, ub, lane);
    u3o<2,5,  10,0>(p, pi_, ub, lane);
  }
  {
    float t = crx_p[1];
    float cc = __cosf(0.5f * t), ss = __sinf(0.5f * t);
    crxo<0,5,  5,2 >(p, pi_, cc, ss, lane);   // (1,3)
    crxo<2,5,  5,0 >(p, pi_, cc, ss, lane);   // (5,7)
    crxo<4,10, 10,1>(p, pi_, cc, ss, lane);   // (3,5)
  }
  {
    float ub[8]; u3_make(u3b_p[3], u3b_p[4], u3b_p[5], ub);
    u3o<0,5,  10,1>(p, pi_, ub, lane);
    u3o<2,5,  10,0>(p, pi_, ub, lane);
  }

  float f2, f3;
  expz_fin(p, pi_, lane, f2, f3);

  // ---- MLP (per half-wave = one element) ----------------------------------
  const int j = (l5 < 15) ? l5 : 0;
  float acc = W1[j * 4 + 0] * f0 + W1[j * 4 + 1] * f1 +
              W1[j * 4 + 2] * f2 + W1[j * 4 + 3] * f3 + b1[j];
  float e2 = __expf(2.0f * acc);
  float th = (e2 - 1.0f) / (e2 + 1.0f);
  float part = (l5 < 15) ? th * W2[j] : 0.0f;
  #pragma unroll
  for (int m = 1; m < 32; m <<= 1) part += __shfl_xor(part, m);

  if (l5 == 0 && elem < B) {
    float z = part + b2[0];
    out[elem] = 1.0f / (1.0f + __expf(-z));
  }
}

extern "C" void kernel_launch(void* const* d_in, const int* in_sizes, int n_in,
                              void* d_out, int out_size, void* d_ws, size_t ws_size,
                              hipStream_t stream) {
  (void)n_in; (void)out_size; (void)d_ws; (void)ws_size;
  const float* x     = (const float*)d_in[0];
  const float* rz_p  = (const float*)d_in[1];
  const float* ry_p  = (const float*)d_in[2];
  const float* ry2_p = (const float*)d_in[3];
  const float* crx_p = (const float*)d_in[4];
  const float* u3_p  = (const float*)d_in[5];
  const float* u3b_p = (const float*)d_in[6];
  const float* W1    = (const float*)d_in[7];
  const float* b1    = (const float*)d_in[8];
  const float* W2    = (const float*)d_in[9];
  const float* b2    = (const float*)d_in[10];
  float* out = (float*)d_out;

  const int B = in_sizes[0] / 32;          // 8192
  const int blocks = (B + 15) / 16;        // 2 elems/wave, 8 waves/block -> 512
  qcnn_kernel<<<dim3(blocks), dim3(512), 0, stream>>>(
      x, rz_p, ry_p, ry2_p, crx_p, u3_p, u3b_p, W1, b1, W2, b2, out, B);
}